// Round 9
// baseline (502.795 us; speedup 1.0000x reference)
//
#include <hip/hip_runtime.h>

typedef _Float16 f16;
typedef _Float16 f16x8 __attribute__((ext_vector_type(8)));
typedef _Float16 f16x4 __attribute__((ext_vector_type(4)));
typedef float    f32x4 __attribute__((ext_vector_type(4)));

#define NB 4
#define SEQ 4096
#define DIM 512
#define MTOT (NB*SEQ)   // 16384
#define NEL ((size_t)MTOT*DIM)
#define WELEM ((size_t)DIM*DIM)

// ---------------------------------------------------------------------------
// global -> LDS direct DMA, 16B per lane. LDS dest wave-uniform; HW adds
// lane*16. Global src per-lane.
// ---------------------------------------------------------------------------
__device__ __forceinline__ void gl_lds16(const f16* g, f16* l)
{
    __builtin_amdgcn_global_load_lds(
        (const __attribute__((address_space(1))) void*)g,
        (__attribute__((address_space(3))) void*)l, 16, 0, 0);
}

// ---------------------------------------------------------------------------
// f32 -> f16 conversion pass: x, y, and the 5 weight matrices.
// Wh layout: [5][512*512], order q, qv, k, kv, f.
// ---------------------------------------------------------------------------
__global__ __launch_bounds__(256) void convert_kernel(
    const float* __restrict__ x, const float* __restrict__ y,
    const float* __restrict__ Wq, const float* __restrict__ Wqv,
    const float* __restrict__ Wk, const float* __restrict__ Wkv,
    const float* __restrict__ Wf,
    f16* __restrict__ xh, f16* __restrict__ yh, f16* __restrict__ Wh)
{
    const size_t q4 = NEL / 4;               // float4 count per big tensor
    const size_t w4 = WELEM / 4;             // per weight matrix
    const size_t total = 2*q4 + 5*w4;
    for (size_t u = (size_t)blockIdx.x*blockDim.x + threadIdx.x; u < total;
         u += (size_t)gridDim.x*blockDim.x) {
        const float* src; f16* dst; size_t off;
        if (u < q4)            { src = x;  dst = xh; off = u; }
        else if (u < 2*q4)     { src = y;  dst = yh; off = u - q4; }
        else {
            size_t w = u - 2*q4;
            int wi = (int)(w / w4); off = w - (size_t)wi*w4;
            src = (wi==0)?Wq:(wi==1)?Wqv:(wi==2)?Wk:(wi==3)?Wkv:Wf;
            dst = Wh + (size_t)wi*WELEM;
        }
        float4 v = ((const float4*)src)[off];
        f16x4 h = { (f16)v.x, (f16)v.y, (f16)v.z, (f16)v.w };
        ((f16x4*)dst)[off] = h;
    }
}

// ---------------------------------------------------------------------------
// f16 projection GEMM (fast path): out[m,n] = f16(sum_k A[m,k]*W[n,k] + b[n])
// DOUBLE-BUFFERED global_load_lds staging, ONE barrier per k-step:
//   issue DMA(k+1) -> buf[(k+1)&1]; ds_read frags(k) from buf[k&1]; MFMA(k);
//   barrier (drains DMA with full compute + multi-block TLP cover).
// Hazards: DMA(k+1) overwrites buf[(k+1)&1], last read iter k-1, separated by
// iter k-1's tail barrier. Unpadded [128][32] tiles: b128 frag reads sit at
// the 8-pass structural floor (64 lanes x 16B) -> no conflict penalty.
// Epilogue scatter layouts (v4 swizzles, verbatim):
//  K: unit = t*2048 + chunk*1024 + n*32 + ((ksl*4+q+n)&31), elem j
//  V: unit = t*2048 + chunk*1024 + dl*4 + ((q+(dl>>1))&3), elem j
// ---------------------------------------------------------------------------
__global__ __launch_bounds__(256) void proj_gemm16(
    const f16* __restrict__ xh, const f16* __restrict__ yh,
    const f16* __restrict__ Wh,
    const float* __restrict__ bq, const float* __restrict__ bqv,
    const float* __restrict__ bk, const float* __restrict__ bkv,
    f16* __restrict__ qh, f16* __restrict__ qvh,
    f16* __restrict__ kS, f16* __restrict__ vS)
{
    __shared__ __attribute__((aligned(16))) f16 a_lds[2][128*32];  // 16 KB
    __shared__ __attribute__((aligned(16))) f16 b_lds[2][128*32];  // 16 KB

    const int p = blockIdx.z;
    const f16* A    = (p < 2) ? xh : yh;
    const f16* W    = Wh + (size_t)p * WELEM;
    const float* bias = (p==0)?bq:(p==1)?bqv:(p==2)?bk:bkv;

    const int m0 = blockIdx.y * 128, n0 = blockIdx.x * 128;
    const int tid = threadIdx.x, lane = tid & 63, wv = tid >> 6;
    const int wm = wv >> 1, wn = wv & 1, mrow = lane & 15, qd = lane >> 4;

    f32x4 acc[4][4];
#pragma unroll
    for (int mt = 0; mt < 4; ++mt)
#pragma unroll
        for (int nt = 0; nt < 4; ++nt) acc[mt][nt] = (f32x4){0.f,0.f,0.f,0.f};

    float bv[4];
#pragma unroll
    for (int nt = 0; nt < 4; ++nt) bv[nt] = bias[n0 + wn*64 + nt*16 + mrow];

    const int srow = lane >> 2, scol = (lane & 3) * 8;  // staging row/col per lane

    // prologue: stage k-step 0 into buf 0
#pragma unroll
    for (int i = 0; i < 2; ++i) {
        int c = wv*2 + i;                               // chunk 0..7 (16 rows)
        gl_lds16(A + (size_t)(m0 + c*16 + srow)*DIM + scol, &a_lds[0][c*512]);
        gl_lds16(W + (size_t)(n0 + c*16 + srow)*DIM + scol, &b_lds[0][c*512]);
    }
    __syncthreads();

    for (int kk = 0; kk < 16; ++kk) {
        // issue next k-step's DMA first (covered by frag reads + MFMA below)
        if (kk < 15) {
            const int k1 = (kk + 1) * 32;
            const int nb = (kk + 1) & 1;
#pragma unroll
            for (int i = 0; i < 2; ++i) {
                int c = wv*2 + i;
                gl_lds16(A + (size_t)(m0 + c*16 + srow)*DIM + k1 + scol, &a_lds[nb][c*512]);
                gl_lds16(W + (size_t)(n0 + c*16 + srow)*DIM + k1 + scol, &b_lds[nb][c*512]);
            }
        }
        const f16* al = &a_lds[kk & 1][0];
        const f16* bl = &b_lds[kk & 1][0];
        f16x8 af[4], bfr[4];
#pragma unroll
        for (int mt = 0; mt < 4; ++mt)
            af[mt]  = *(const f16x8*)&al[(wm*64 + mt*16 + mrow)*32 + qd*8];
#pragma unroll
        for (int nt = 0; nt < 4; ++nt)
            bfr[nt] = *(const f16x8*)&bl[(wn*64 + nt*16 + mrow)*32 + qd*8];
#pragma unroll
        for (int mt = 0; mt < 4; ++mt)
#pragma unroll
            for (int nt = 0; nt < 4; ++nt)
                acc[mt][nt] = __builtin_amdgcn_mfma_f32_16x16x32_f16(af[mt], bfr[nt], acc[mt][nt], 0,0,0);
        __syncthreads();   // sole barrier: buf[kk&1] reads done + DMA(kk+1) drained
    }

#pragma unroll
    for (int mt = 0; mt < 4; ++mt)
#pragma unroll
        for (int r = 0; r < 4; ++r) {
            int g = m0 + wm*64 + mt*16 + qd*4 + r;
#pragma unroll
            for (int nt = 0; nt < 4; ++nt) {
                int d = n0 + wn*64 + nt*16 + mrow;
                f16 val = (f16)(acc[mt][nt][r] + bv[nt]);
                if (p == 0) {
                    qh[(size_t)g*DIM + d] = val;
                } else if (p == 1) {
                    qvh[(size_t)g*DIM + d] = val;
                } else if (p == 2) {
                    int b = g >> 12, s = g & 4095;
                    int t = s >> 5, n = s & 31;
                    int chunk = d >> 8, ksl = (d >> 5) & 7, q = (d >> 3) & 3, j = d & 7;
                    size_t idx = (((size_t)((b*128 + t)*2048 + chunk*1024
                                   + n*32 + ((ksl*4 + q + n) & 31))) << 3) + j;
                    kS[idx] = val;
                } else {
                    int b = g >> 12, s = g & 4095;
                    int t = s >> 5, q = (s >> 3) & 3, j = s & 7;
                    int chunk = d >> 8, dl = d & 255;
                    size_t idx = (((size_t)((b*128 + t)*2048 + chunk*1024
                                   + dl*4 + ((q + (dl >> 1)) & 3))) << 3) + j;
                    vS[idx] = val;
                }
            }
        }
}

// ---------------------------------------------------------------------------
// f16 final GEMM (fast path): out f32 = sum_k ao[m,k]*Wf[n,k] + bf[n]
// Same double-buffered single-barrier k-loop.
// ---------------------------------------------------------------------------
__global__ __launch_bounds__(256) void final_gemm16(
    const f16* __restrict__ ao, const f16* __restrict__ Wfh,
    const float* __restrict__ bf, float* __restrict__ out)
{
    __shared__ __attribute__((aligned(16))) f16 a_lds[2][128*32];
    __shared__ __attribute__((aligned(16))) f16 b_lds[2][128*32];

    const int m0 = blockIdx.y * 128, n0 = blockIdx.x * 128;
    const int tid = threadIdx.x, lane = tid & 63, wv = tid >> 6;
    const int wm = wv >> 1, wn = wv & 1, mrow = lane & 15, qd = lane >> 4;

    f32x4 acc[4][4];
#pragma unroll
    for (int mt = 0; mt < 4; ++mt)
#pragma unroll
        for (int nt = 0; nt < 4; ++nt) acc[mt][nt] = (f32x4){0.f,0.f,0.f,0.f};

    float bv[4];
#pragma unroll
    for (int nt = 0; nt < 4; ++nt) bv[nt] = bf[n0 + wn*64 + nt*16 + mrow];

    const int srow = lane >> 2, scol = (lane & 3) * 8;

    // prologue: stage k-step 0 into buf 0
#pragma unroll
    for (int i = 0; i < 2; ++i) {
        int c = wv*2 + i;
        gl_lds16(ao  + (size_t)(m0 + c*16 + srow)*DIM + scol, &a_lds[0][c*512]);
        gl_lds16(Wfh + (size_t)(n0 + c*16 + srow)*DIM + scol, &b_lds[0][c*512]);
    }
    __syncthreads();

    for (int kk = 0; kk < 16; ++kk) {
        if (kk < 15) {
            const int k1 = (kk + 1) * 32;
            const int nb = (kk + 1) & 1;
#pragma unroll
            for (int i = 0; i < 2; ++i) {
                int c = wv*2 + i;
                gl_lds16(ao  + (size_t)(m0 + c*16 + srow)*DIM + k1 + scol, &a_lds[nb][c*512]);
                gl_lds16(Wfh + (size_t)(n0 + c*16 + srow)*DIM + k1 + scol, &b_lds[nb][c*512]);
            }
        }
        const f16* al = &a_lds[kk & 1][0];
        const f16* bl = &b_lds[kk & 1][0];
        f16x8 af[4], bfr[4];
#pragma unroll
        for (int mt = 0; mt < 4; ++mt)
            af[mt]  = *(const f16x8*)&al[(wm*64 + mt*16 + mrow)*32 + qd*8];
#pragma unroll
        for (int nt = 0; nt < 4; ++nt)
            bfr[nt] = *(const f16x8*)&bl[(wn*64 + nt*16 + mrow)*32 + qd*8];
#pragma unroll
        for (int mt = 0; mt < 4; ++mt)
#pragma unroll
            for (int nt = 0; nt < 4; ++nt)
                acc[mt][nt] = __builtin_amdgcn_mfma_f32_16x16x32_f16(af[mt], bfr[nt], acc[mt][nt], 0,0,0);
        __syncthreads();
    }
#pragma unroll
    for (int mt = 0; mt < 4; ++mt)
#pragma unroll
        for (int r = 0; r < 4; ++r) {
            size_t grow = (size_t)(m0 + wm*64 + mt*16 + qd*4 + r) * DIM;
#pragma unroll
            for (int nt = 0; nt < 4; ++nt) {
                int col = n0 + wn*64 + nt*16 + mrow;
                out[grow + col] = acc[mt][nt][r] + bv[nt];
            }
        }
}

// ---------------------------------------------------------------------------
// FALLBACK projection GEMM (f32 inputs, reg-convert staging) — proven v4 path,
// used only if ws_size can't hold the f16 copies.
// ---------------------------------------------------------------------------
__global__ __launch_bounds__(256) void proj_gemm(
    const float* __restrict__ x, const float* __restrict__ y,
    const float* __restrict__ Wq, const float* __restrict__ bq,
    const float* __restrict__ Wqv, const float* __restrict__ bqv,
    const float* __restrict__ Wk, const float* __restrict__ bk,
    const float* __restrict__ Wkv, const float* __restrict__ bkv,
    f16* __restrict__ qh, f16* __restrict__ qvh,
    f16* __restrict__ kS, f16* __restrict__ vS)
{
    __shared__ __attribute__((aligned(16))) f16 a_lds[128][40];
    __shared__ __attribute__((aligned(16))) f16 b_lds[128][40];

    const int p = blockIdx.z;
    const float* A    = (p < 2) ? x : y;
    const float* W    = (p==0)?Wq:(p==1)?Wqv:(p==2)?Wk:Wkv;
    const float* bias = (p==0)?bq:(p==1)?bqv:(p==2)?bk:bkv;

    const int m0 = blockIdx.y * 128, n0 = blockIdx.x * 128;
    const int tid = threadIdx.x, lane = tid & 63, wv = tid >> 6;
    const int wm = wv >> 1, wn = wv & 1, mrow = lane & 15, qd = lane >> 4;

    f32x4 acc[4][4];
#pragma unroll
    for (int mt = 0; mt < 4; ++mt)
#pragma unroll
        for (int nt = 0; nt < 4; ++nt) acc[mt][nt] = (f32x4){0.f,0.f,0.f,0.f};

    float bv[4];
#pragma unroll
    for (int nt = 0; nt < 4; ++nt) bv[nt] = bias[n0 + wn*64 + nt*16 + mrow];

    for (int k0 = 0; k0 < DIM; k0 += 32) {
        __syncthreads();
#pragma unroll
        for (int i = 0; i < 4; ++i) {
            int c = i*256 + tid;
            int row = c >> 3, c4 = c & 7;
            float4 v = *(const float4*)(A + (size_t)(m0+row)*DIM + k0 + c4*4);
            f16x4 hh = { (f16)v.x, (f16)v.y, (f16)v.z, (f16)v.w };
            *(f16x4*)&a_lds[row][c4*4] = hh;
        }
#pragma unroll
        for (int i = 0; i < 4; ++i) {
            int c = i*256 + tid;
            int row = c >> 3, c4 = c & 7;
            float4 v = *(const float4*)(W + (size_t)(n0+row)*DIM + k0 + c4*4);
            f16x4 hh = { (f16)v.x, (f16)v.y, (f16)v.z, (f16)v.w };
            *(f16x4*)&b_lds[row][c4*4] = hh;
        }
        __syncthreads();
        f16x8 af[4], bfr[4];
#pragma unroll
        for (int mt = 0; mt < 4; ++mt) af[mt]  = *(const f16x8*)&a_lds[wm*64 + mt*16 + mrow][qd*8];
#pragma unroll
        for (int nt = 0; nt < 4; ++nt) bfr[nt] = *(const f16x8*)&b_lds[wn*64 + nt*16 + mrow][qd*8];
#pragma unroll
        for (int mt = 0; mt < 4; ++mt)
#pragma unroll
            for (int nt = 0; nt < 4; ++nt)
                acc[mt][nt] = __builtin_amdgcn_mfma_f32_16x16x32_f16(af[mt], bfr[nt], acc[mt][nt], 0,0,0);
    }

#pragma unroll
    for (int mt = 0; mt < 4; ++mt)
#pragma unroll
        for (int r = 0; r < 4; ++r) {
            int g = m0 + wm*64 + mt*16 + qd*4 + r;
#pragma unroll
            for (int nt = 0; nt < 4; ++nt) {
                int d = n0 + wn*64 + nt*16 + mrow;
                f16 val = (f16)(acc[mt][nt][r] + bv[nt]);
                if (p == 0) {
                    qh[(size_t)g*DIM + d] = val;
                } else if (p == 1) {
                    qvh[(size_t)g*DIM + d] = val;
                } else if (p == 2) {
                    int b = g >> 12, s = g & 4095;
                    int t = s >> 5, n = s & 31;
                    int chunk = d >> 8, ksl = (d >> 5) & 7, q = (d >> 3) & 3, j = d & 7;
                    size_t idx = (((size_t)((b*128 + t)*2048 + chunk*1024
                                   + n*32 + ((ksl*4 + q + n) & 31))) << 3) + j;
                    kS[idx] = val;
                } else {
                    int b = g >> 12, s = g & 4095;
                    int t = s >> 5, q = (s >> 3) & 3, j = s & 7;
                    int chunk = d >> 8, dl = d & 255;
                    size_t idx = (((size_t)((b*128 + t)*2048 + chunk*1024
                                   + dl*4 + ((q + (dl >> 1)) & 3))) << 3) + j;
                    vS[idx] = val;
                }
            }
        }
}

// ---------------------------------------------------------------------------
// Flash attention v4 (proven best, verbatim): 256 blocks (1/CU), 512 threads /
// 8 waves = 2 waves/SIMD. D-split pairs (qg, qg+4), ONE barrier per iteration,
// software-pipelined partial-S. Exchange slots double as P-transpose scratch.
// LDS: 64K kbuf + 64K vbuf + 32K xch = 163840 B (exactly 160 KiB).
// ---------------------------------------------------------------------------
__global__ __launch_bounds__(512, 2) void attn_kernel(
    const f16* __restrict__ qh, const f16* __restrict__ kS,
    const f16* __restrict__ vS, const f16* __restrict__ qvh,
    f16* __restrict__ ao)
{
    __shared__ __attribute__((aligned(16))) f16 kbuf[2][16384];   // 2 x 32KB
    __shared__ __attribute__((aligned(16))) f16 vbuf[2][16384];   // 2 x 32KB
    __shared__ __attribute__((aligned(16))) float xch[2][4][2][512]; // 32KB

    const int xcd = blockIdx.x & 7;
    const int b   = xcd >> 1;                          // batch -> XCD pair
    const int qt  = (blockIdx.x >> 3) * 2 + (xcd & 1); // 0..63
    const int tid = threadIdx.x, lane = tid & 63, w = tid >> 6;
    const int qg = w & 3, h = w >> 2;                  // Q group / d-half
    const int mrow = lane & 15, qd = lane >> 4;

    const f16* kSb = kS + ((size_t)b << 21);
    const f16* vSb = vS + ((size_t)b << 21);

    // Q fragments for this wave's 256-d half (A-layout)
    const size_t qrow = ((size_t)b*SEQ + qt*64 + qg*16 + mrow) * DIM;
    f16x8 qf[8];
#pragma unroll
    for (int i = 0; i < 8; ++i)
        qf[i] = *(const f16x8*)(qh + qrow + (h*8 + i)*32 + qd*8);

    f32x4 o[16];
#pragma unroll
    for (int nt = 0; nt < 16; ++nt) o[nt] = (f32x4){0.f,0.f,0.f,0.f};
    f32x4 o_l = (f32x4){0.f,0.f,0.f,0.f};
    float m_i[4] = {-INFINITY,-INFINITY,-INFINITY,-INFINITY};
    const f16x8 ones = {(f16)1.f,(f16)1.f,(f16)1.f,(f16)1.f,
                        (f16)1.f,(f16)1.f,(f16)1.f,(f16)1.f};

    const int n0a = mrow, n1a = 16 + mrow;
    const int cbase = h * 1024;                        // unit base of d-half chunk

    // prologue: DMA K0->kbuf0, V0->vbuf0, K1->kbuf1 (12 DMA/wave)
#pragma unroll
    for (int u = 0; u < 4; ++u) {
        const int ub = (u*8 + w) * 64;
        gl_lds16(kSb + (size_t)(ub + lane)*8,        (f16*)&kbuf[0][ub*8]);
    }
#pragma unroll
    for (int u = 0; u < 4; ++u) {
        const int ub = (u*8 + w) * 64;
        gl_lds16(vSb + (size_t)(ub + lane)*8,        (f16*)&vbuf[0][ub*8]);
    }
#pragma unroll
    for (int u = 0; u < 4; ++u) {
        const int ub = (u*8 + w) * 64;
        gl_lds16(kSb + (size_t)(2048 + ub + lane)*8, (f16*)&kbuf[1][ub*8]);
    }
    __syncthreads();

    // partial S_0 from kbuf[0]
    f32x4 s0p = (f32x4){0.f,0.f,0.f,0.f}, s1p = s0p;
    {
        const f16* kb = &kbuf[0][0];
#pragma unroll
        for (int ksl = 0; ksl < 8; ++ksl) {
            f16x8 kf0 = *(const f16x8*)&kb[(cbase + n0a*32 + ((ksl*4 + qd + n0a) & 31)) << 3];
            f16x8 kf1 = *(const f16x8*)&kb[(cbase + n1a*32 + ((ksl*4 + qd + n1a) & 31)) << 3];
            s0p = __builtin_amdgcn_mfma_f32_16x16x32_f16(qf[ksl], kf0, s0p, 0,0,0);
            s1p = __builtin_amdgcn_mfma_f32_16x16x32_f16(qf[ksl], kf1, s1p, 0,0,0);
        }
        f32x4* slot0 = (f32x4*)&xch[0][qg][h][0];
        slot0[lane]      = s0p;
        slot0[64 + lane] = s1p;
    }
    __syncthreads();

    for (int j = 0; j < 128; ++j) {
        // --- top: prefetch K(j+2) and V(j+1); drained at THIS iter's tail ---
        {
            const size_t tk = (size_t)((j + 2) & 127) * 2048;
            const size_t tv = (size_t)((j + 1) & 127) * 2048;
            f16* kd = &kbuf[j & 1][0];
            f16* vd = &vbuf[(j + 1) & 1][0];
#pragma unroll
            for (int u = 0; u < 4; ++u) {
                const int ub = (u*8 + w) * 64;
                gl_lds16(kSb + (tk + ub + lane)*8, kd + ub*8);
                gl_lds16(vSb + (tv + ub + lane)*8, vd + ub*8);
            }
        }

        // --- exchange: partner partial S_j (written iter j-1) + own regs ---
        float* slotr = &xch[j & 1][qg][h ^ 1][0];
        f32x4 s0 = ((const f32x4*)slotr)[lane];
        f32x4 s1 = ((const f32x4*)slotr)[64 + lane];
#pragma unroll
        for (int rr = 0; rr < 4; ++rr) { s0[rr] += s0p[rr]; s1[rr] += s1p[rr]; }

        // --- online softmax with defer-max (THR=8) ---
        float pm[4];
        bool need = false;
#pragma unroll
        for (int rr = 0; rr < 4; ++rr) {
            float v = fmaxf(s0[rr], s1[rr]);
            v = fmaxf(v, __shfl_xor(v, 1));
            v = fmaxf(v, __shfl_xor(v, 2));
            v = fmaxf(v, __shfl_xor(v, 4));
            v = fmaxf(v, __shfl_xor(v, 8));
            pm[rr] = v;
            if (v > m_i[rr] + 8.f) need = true;
        }
        if (__any(need)) {
#pragma unroll
            for (int rr = 0; rr < 4; ++rr) {
                float mn = fmaxf(m_i[rr], pm[rr]);
                float alpha = __expf(m_i[rr] - mn);
                m_i[rr] = mn;
#pragma unroll
                for (int nt = 0; nt < 16; ++nt) o[nt][rr] *= alpha;
                o_l[rr] *= alpha;
            }
        }
#pragma unroll
        for (int rr = 0; rr < 4; ++rr) {
            s0[rr] = __expf(s0[rr] - m_i[rr]);   // bounded by e^8
            s1[rr] = __expf(s1[rr] - m_i[rr]);
        }

        // --- P: C-layout -> A-layout via slot reuse (self-ordered in-wave) ---
        f16* pb = (f16*)slotr;                      // 16 rows x 40 f16 view
#pragma unroll
        for (int rr = 0; rr < 4; ++rr) {
            pb[(qd*4 + rr)*40 + mrow]      = (f16)s0[rr];
            pb[(qd*4 + rr)*40 + 16 + mrow] = (f16)s1[rr];
        }
        f16x8 pf = *(const f16x8*)&pb[mrow*40 + qd*8];
        o_l = __builtin_amdgcn_mfma_f32_16x16x32_f16(pf, ones, o_l, 0,0,0);

        // --- O_half += P @ V_half : 16 d-tiles ---
        {
            const f16* vb = &vbuf[j & 1][0];
#pragma unroll
            for (int nt = 0; nt < 16; ++nt) {
                int dl = nt*16 + mrow;              // d = h*256 + dl
                f16x8 vf = *(const f16x8*)&vb[(cbase + dl*4 + ((qd + (dl >> 1)) & 3)) << 3];
                o[nt] = __builtin_amdgcn_mfma_f32_16x16x32_f16(pf, vf, o[nt], 0,0,0);
            }
        }

        // --- partial S_{j+1} from kbuf[(j+1)&1] ---
        if (j < 127) {
            const f16* kb = &kbuf[(j + 1) & 1][0];
            f32x4 a0 = (f32x4){0.f,0.f,0.f,0.f}, a1 = a0;
#pragma unroll
            for (int ksl = 0; ksl < 8; ++ksl) {
                f16x8 kf0 = *(const f16x8*)&kb[(cbase + n0a*32 + ((ksl*4 + qd + n0a) & 31)) << 3];
                f16x8 kf1 = *(const f16x8*)&kb[(cbase + n1a*32 + ((ksl*4 + qd + n1a) & 31)) << 3];
                a0 = __builtin_amdgcn_mfma_f32_16x16x32_f16(qf[ksl], kf0, a0, 0,0,0);
                a1 = __builtin_amdgcn_mfma_f32_16x16x32_f16(qf[ksl], kf1, a1, 0,0,0);
            }
            s0p = a0; s1p = a1;
            f32x4* slotw = (f32x4*)&xch[(j + 1) & 1][qg][h][0];
            slotw[lane]      = s0p;
            slotw[64 + lane] = s1p;
        }

        __syncthreads();   // sole barrier: xch visible + DMA drained (full cover)
    }

    // epilogue: each wave owns rows [qg*16,+16) x cols [h*256,+256) fully
#pragma unroll
    for (int rr = 0; rr < 4; ++rr) {
        float inv_l = 1.f / o_l[rr];
        size_t grow = ((size_t)b*SEQ + qt*64 + qg*16 + qd*4 + rr) * DIM + h*256;
#pragma unroll
        for (int nt = 0; nt < 16; ++nt) {
            int col = nt*16 + mrow;
            float val = o[nt][rr] * inv_l + (float)qvh[grow + col];
            ao[grow + col] = (f16)val;
        }
    }
}

// ---------------------------------------------------------------------------
// FALLBACK final linear (f32 W): out = sum_k ao[m,k]*Wf[n,k] + bf[n]
// ---------------------------------------------------------------------------
__global__ __launch_bounds__(256) void final_gemm(
    const f16* __restrict__ ao, const float* __restrict__ Wf,
    const float* __restrict__ bf, float* __restrict__ out)
{
    __shared__ __attribute__((aligned(16))) f16 a_lds[128][40];
    __shared__ __attribute__((aligned(16))) f16 b_lds[128][40];

    const int m0 = blockIdx.y * 128, n0 = blockIdx.x * 128;
    const int tid = threadIdx.x, lane = tid & 63, wv = tid >> 6;
    const int wm = wv >> 1, wn = wv & 1, mrow = lane & 15, qd = lane >> 4;

    f32x4 acc[4][4];
#pragma unroll
    for (int mt = 0; mt < 4; ++mt)
#pragma unroll
        for (int nt = 0; nt < 4; ++nt) acc[mt][nt] = (f32x4){0.f,0.f,0.f,0.f};

    float bv[4];
#pragma unroll
    for (int nt = 0; nt < 4; ++nt) bv[nt] = bf[n0 + wn*64 + nt*16 + mrow];

    for (int k0 = 0; k0 < DIM; k0 += 32) {
        __syncthreads();
#pragma unroll
        for (int i = 0; i < 2; ++i) {
            int c = i*256 + tid;
            int row = c >> 2, c8 = c & 3;
            *(f16x8*)&a_lds[row][c8*8] =
                *(const f16x8*)(ao + (size_t)(m0+row)*DIM + k0 + c8*8);
        }
#pragma unroll
        for (int i = 0; i < 4; ++i) {
            int c = i*256 + tid;
            int row = c >> 3, c4 = c & 7;
            float4 v = *(const float4*)(Wf + (size_t)(n0+row)*DIM + k0 + c4*4);
            f16x4 hh = { (f16)v.x, (f16)v.y, (f16)v.z, (f16)v.w };
            *(f16x4*)&b_lds[row][c4*4] = hh;
        }
        __syncthreads();
        f16x8 af[4], bfr[4];
#pragma unroll
        for (int mt = 0; mt < 4; ++mt) af[mt]  = *(const f16x8*)&a_lds[wm*64 + mt*16 + mrow][qd*8];
#pragma unroll
        for (int nt = 0; nt < 4; ++nt) bfr[nt] = *(const f16x8*)&b_lds[wn*64 + nt*16 + mrow][qd*8];
#pragma unroll
        for (int mt = 0; mt < 4; ++mt)
#pragma unroll
            for (int nt = 0; nt < 4; ++nt)
                acc[mt][nt] = __builtin_amdgcn_mfma_f32_16x16x32_f16(af[mt], bfr[nt], acc[mt][nt], 0,0,0);
    }
#pragma unroll
    for (int mt = 0; mt < 4; ++mt)
#pragma unroll
        for (int r = 0; r < 4; ++r) {
            size_t grow = (size_t)(m0 + wm*64 + mt*16 + qd*4 + r) * DIM;
#pragma unroll
            for (int nt = 0; nt < 4; ++nt) {
                int col = n0 + wn*64 + nt*16 + mrow;
                out[grow + col] = acc[mt][nt][r] + bv[nt];
            }
        }
}

// ---------------------------------------------------------------------------
extern "C" void kernel_launch(void* const* d_in, const int* in_sizes, int n_in,
                              void* d_out, int out_size, void* d_ws, size_t ws_size,
                              hipStream_t stream)
{
    const float* x   = (const float*)d_in[0];
    const float* y   = (const float*)d_in[1];
    const float* Wq  = (const float*)d_in[2];
    const float* bq  = (const float*)d_in[3];
    const float* Wqv = (const float*)d_in[4];
    const float* bqv = (const float*)d_in[5];
    const float* Wk  = (const float*)d_in[6];
    const float* bk  = (const float*)d_in[7];
    const float* Wkv = (const float*)d_in[8];
    const float* bkv = (const float*)d_in[9];
    const float* Wf  = (const float*)d_in[10];
    const float* bf  = (const float*)d_in[11];
    float* out = (float*)d_out;

    f16* qh  = (f16*)d_ws;       // base: 5 x NEL f16 = 84 MB (proven layout)
    f16* qvh = qh  + NEL;
    f16* kS  = qvh + NEL;
    f16* vS  = kS  + NEL;
    f16* aob = vS  + NEL;
    // fast-path extras:
    f16* xh  = aob + NEL;
    f16* yh  = xh  + NEL;
    f16* Wh  = yh  + NEL;        // [5][512*512]

    const size_t need_fast = (7*NEL + 5*WELEM) * sizeof(f16);
    const bool fast = (ws_size >= need_fast);

    if (fast) {
        convert_kernel<<<2048, 256, 0, stream>>>(x, y, Wq, Wqv, Wk, Wkv, Wf, xh, yh, Wh);
        proj_gemm16<<<dim3(4, 128, 4), 256, 0, stream>>>(
            xh, yh, Wh, bq, bqv, bk, bkv, qh, qvh, kS, vS);
    } else {
        proj_gemm<<<dim3(4, 128, 4), 256, 0, stream>>>(
            x, y, Wq, bq, Wqv, bqv, Wk, bk, Wkv, bkv, qh, qvh, kS, vS);
    }

    attn_kernel<<<dim3(256), 512, 0, stream>>>(qh, kS, vS, qvh, aob);

    if (fast) {
        final_gemm16<<<dim3(4, 128), 256, 0, stream>>>(aob, Wh + 4*WELEM, bf, out);
    } else {
        final_gemm<<<dim3(4, 128), 256, 0, stream>>>(aob, Wf, bf, out);
    }
}

// Round 10
// 493.742 us; speedup vs baseline: 1.0183x; 1.0183x over previous
//
#include <hip/hip_runtime.h>

typedef _Float16 f16;
typedef _Float16 f16x8 __attribute__((ext_vector_type(8)));
typedef _Float16 f16x4 __attribute__((ext_vector_type(4)));
typedef float    f32x4 __attribute__((ext_vector_type(4)));

#define NB 4
#define SEQ 4096
#define DIM 512
#define MTOT (NB*SEQ)   // 16384
#define NEL ((size_t)MTOT*DIM)
#define WELEM ((size_t)DIM*DIM)

// ---------------------------------------------------------------------------
// global -> LDS direct DMA, 16B per lane. LDS dest wave-uniform; HW adds
// lane*16. Global src per-lane.
// ---------------------------------------------------------------------------
__device__ __forceinline__ void gl_lds16(const f16* g, f16* l)
{
    __builtin_amdgcn_global_load_lds(
        (const __attribute__((address_space(1))) void*)g,
        (__attribute__((address_space(3))) void*)l, 16, 0, 0);
}

// ---------------------------------------------------------------------------
// f32 -> f16 conversion pass: x, y, and the 5 weight matrices.
// Wh layout: [5][512*512], order q, qv, k, kv, f.
// ---------------------------------------------------------------------------
__global__ __launch_bounds__(256) void convert_kernel(
    const float* __restrict__ x, const float* __restrict__ y,
    const float* __restrict__ Wq, const float* __restrict__ Wqv,
    const float* __restrict__ Wk, const float* __restrict__ Wkv,
    const float* __restrict__ Wf,
    f16* __restrict__ xh, f16* __restrict__ yh, f16* __restrict__ Wh)
{
    const size_t q4 = NEL / 4;               // float4 count per big tensor
    const size_t w4 = WELEM / 4;             // per weight matrix
    const size_t total = 2*q4 + 5*w4;
    for (size_t u = (size_t)blockIdx.x*blockDim.x + threadIdx.x; u < total;
         u += (size_t)gridDim.x*blockDim.x) {
        const float* src; f16* dst; size_t off;
        if (u < q4)            { src = x;  dst = xh; off = u; }
        else if (u < 2*q4)     { src = y;  dst = yh; off = u - q4; }
        else {
            size_t w = u - 2*q4;
            int wi = (int)(w / w4); off = w - (size_t)wi*w4;
            src = (wi==0)?Wq:(wi==1)?Wqv:(wi==2)?Wk:(wi==3)?Wkv:Wf;
            dst = Wh + (size_t)wi*WELEM;
        }
        float4 v = ((const float4*)src)[off];
        f16x4 h = { (f16)v.x, (f16)v.y, (f16)v.z, (f16)v.w };
        ((f16x4*)dst)[off] = h;
    }
}

// ---------------------------------------------------------------------------
// f16 projection GEMM: out[m,n] = f16(sum_k A[m,k]*W[n,k] + b[n])
// Double-buffered global_load_lds staging; ONE barrier per k-step.
// NEW: kS/vS epilogues repack through LDS (staging buffers reused) so global
// stores are coalesced f16x8 runs instead of 2-byte 256B-stride scatter.
// Compact LDS indices (bijective, verified):
//  kS: ci = t*512 + n*16 + ((d>>3)&15); out unit s = (kb*4 + n + idx)&31,
//      kb = (n0>>5)&7 in {0,4} (no wrap).
//  vS: ci = t*512 + (dl&127)*4 + ((q+(dl>>1))&3); block window is identity-
//      contiguous: dst unit = tilebase + (n0&255)*4 + rem.
// ---------------------------------------------------------------------------
__global__ __launch_bounds__(256) void proj_gemm16(
    const f16* __restrict__ xh, const f16* __restrict__ yh,
    const f16* __restrict__ Wh,
    const float* __restrict__ bq, const float* __restrict__ bqv,
    const float* __restrict__ bk, const float* __restrict__ bkv,
    f16* __restrict__ qh, f16* __restrict__ qvh,
    f16* __restrict__ kS, f16* __restrict__ vS)
{
    __shared__ __attribute__((aligned(16))) f16 smem[16384];   // 32 KB
    f16* a_lds = smem;            // [2][128*32]
    f16* b_lds = smem + 8192;     // [2][128*32]

    const int p = blockIdx.z;
    const f16* A    = (p < 2) ? xh : yh;
    const f16* W    = Wh + (size_t)p * WELEM;
    const float* bias = (p==0)?bq:(p==1)?bqv:(p==2)?bk:bkv;

    const int m0 = blockIdx.y * 128, n0 = blockIdx.x * 128;
    const int tid = threadIdx.x, lane = tid & 63, wv = tid >> 6;
    const int wm = wv >> 1, wn = wv & 1, mrow = lane & 15, qd = lane >> 4;

    f32x4 acc[4][4];
#pragma unroll
    for (int mt = 0; mt < 4; ++mt)
#pragma unroll
        for (int nt = 0; nt < 4; ++nt) acc[mt][nt] = (f32x4){0.f,0.f,0.f,0.f};

    float bv[4];
#pragma unroll
    for (int nt = 0; nt < 4; ++nt) bv[nt] = bias[n0 + wn*64 + nt*16 + mrow];

    const int srow = lane >> 2, scol = (lane & 3) * 8;  // staging row/col per lane

    // prologue: stage k-step 0 into buf 0
#pragma unroll
    for (int i = 0; i < 2; ++i) {
        int c = wv*2 + i;                               // chunk 0..7 (16 rows)
        gl_lds16(A + (size_t)(m0 + c*16 + srow)*DIM + scol, &a_lds[c*512]);
        gl_lds16(W + (size_t)(n0 + c*16 + srow)*DIM + scol, &b_lds[c*512]);
    }
    __syncthreads();

    for (int kk = 0; kk < 16; ++kk) {
        if (kk < 15) {
            const int k1 = (kk + 1) * 32;
            const int nb = (kk + 1) & 1;
#pragma unroll
            for (int i = 0; i < 2; ++i) {
                int c = wv*2 + i;
                gl_lds16(A + (size_t)(m0 + c*16 + srow)*DIM + k1 + scol, &a_lds[nb*4096 + c*512]);
                gl_lds16(W + (size_t)(n0 + c*16 + srow)*DIM + k1 + scol, &b_lds[nb*4096 + c*512]);
            }
        }
        const f16* al = &a_lds[(kk & 1)*4096];
        const f16* bl = &b_lds[(kk & 1)*4096];
        f16x8 af[4], bfr[4];
#pragma unroll
        for (int mt = 0; mt < 4; ++mt)
            af[mt]  = *(const f16x8*)&al[(wm*64 + mt*16 + mrow)*32 + qd*8];
#pragma unroll
        for (int nt = 0; nt < 4; ++nt)
            bfr[nt] = *(const f16x8*)&bl[(wn*64 + nt*16 + mrow)*32 + qd*8];
#pragma unroll
        for (int mt = 0; mt < 4; ++mt)
#pragma unroll
            for (int nt = 0; nt < 4; ++nt)
                acc[mt][nt] = __builtin_amdgcn_mfma_f32_16x16x32_f16(af[mt], bfr[nt], acc[mt][nt], 0,0,0);
        __syncthreads();   // sole barrier per k-step
    }

    if (p < 2) {
        // q/qv: direct stores (16-lane 32B runs — acceptably coalesced)
        f16* dstb = (p == 0) ? qh : qvh;
#pragma unroll
        for (int mt = 0; mt < 4; ++mt)
#pragma unroll
            for (int r = 0; r < 4; ++r) {
                int g = m0 + wm*64 + mt*16 + qd*4 + r;
#pragma unroll
                for (int nt = 0; nt < 4; ++nt) {
                    int d = n0 + wn*64 + nt*16 + mrow;
                    dstb[(size_t)g*DIM + d] = (f16)(acc[mt][nt][r] + bv[nt]);
                }
            }
    } else if (p == 2) {
        // ---- kS: repack into LDS (compact), then coalesced copy-out ----
        const int kb = (n0 >> 5) & 7;                   // in {0,4}
#pragma unroll
        for (int mt = 0; mt < 4; ++mt)
#pragma unroll
            for (int r = 0; r < 4; ++r) {
                int trow = wm*64 + mt*16 + qd*4 + r;    // local row 0..127
                int t = trow >> 5, n = trow & 31;
#pragma unroll
                for (int nt = 0; nt < 4; ++nt) {
                    int d = n0 + wn*64 + nt*16 + mrow;
                    int idx = (d >> 3) & 15, j = d & 7;
                    smem[(size_t)(t*512 + n*16 + idx)*8 + j] =
                        (f16)(acc[mt][nt][r] + bv[nt]);
                }
            }
        __syncthreads();
        {
            const int b = m0 >> 12;
            const int t0 = (m0 & 4095) >> 5;
            const int chunk = n0 >> 8;
#pragma unroll
            for (int uu = 0; uu < 8; ++uu) {
                int u = uu*256 + tid;                   // 0..2047 units
                int t = u >> 9, rem = u & 511;
                int n = rem >> 4, idx = rem & 15;
                int s = (kb*4 + n + idx) & 31;
                size_t dstu = ((size_t)(b*128 + t0 + t)*2048 + (size_t)chunk*1024
                               + n*32 + s);
                *(f16x8*)&kS[dstu*8] = *(const f16x8*)&smem[(size_t)u*8];
            }
        }
    } else {
        // ---- vS: repack into LDS (identity-contiguous window) ----
#pragma unroll
        for (int mt = 0; mt < 4; ++mt)
#pragma unroll
            for (int r = 0; r < 4; ++r) {
                int trow = wm*64 + mt*16 + qd*4 + r;
                int t = trow >> 5, sr = trow & 31;
                int q = (sr >> 3) & 3, j = sr & 7;
#pragma unroll
                for (int nt = 0; nt < 4; ++nt) {
                    int d = n0 + wn*64 + nt*16 + mrow;
                    int dl = d & 255;
                    smem[(size_t)(t*512 + (dl & 127)*4 + ((q + (dl >> 1)) & 3))*8 + j] =
                        (f16)(acc[mt][nt][r] + bv[nt]);
                }
            }
        __syncthreads();
        {
            const int b = m0 >> 12;
            const int t0 = (m0 & 4095) >> 5;
            const int chunk = n0 >> 8;
            const int wbase = (n0 & 255) * 4;           // window base units
#pragma unroll
            for (int uu = 0; uu < 8; ++uu) {
                int u = uu*256 + tid;
                int t = u >> 9, rem = u & 511;
                size_t dstu = ((size_t)(b*128 + t0 + t)*2048 + (size_t)chunk*1024
                               + wbase + rem);
                *(f16x8*)&vS[dstu*8] = *(const f16x8*)&smem[(size_t)u*8];
            }
        }
    }
}

// ---------------------------------------------------------------------------
// f16 final GEMM: out f32 = sum_k ao[m,k]*Wf[n,k] + bf[n]
// ---------------------------------------------------------------------------
__global__ __launch_bounds__(256) void final_gemm16(
    const f16* __restrict__ ao, const f16* __restrict__ Wfh,
    const float* __restrict__ bf, float* __restrict__ out)
{
    __shared__ __attribute__((aligned(16))) f16 a_lds[2][128*32];
    __shared__ __attribute__((aligned(16))) f16 b_lds[2][128*32];

    const int m0 = blockIdx.y * 128, n0 = blockIdx.x * 128;
    const int tid = threadIdx.x, lane = tid & 63, wv = tid >> 6;
    const int wm = wv >> 1, wn = wv & 1, mrow = lane & 15, qd = lane >> 4;

    f32x4 acc[4][4];
#pragma unroll
    for (int mt = 0; mt < 4; ++mt)
#pragma unroll
        for (int nt = 0; nt < 4; ++nt) acc[mt][nt] = (f32x4){0.f,0.f,0.f,0.f};

    float bv[4];
#pragma unroll
    for (int nt = 0; nt < 4; ++nt) bv[nt] = bf[n0 + wn*64 + nt*16 + mrow];

    const int srow = lane >> 2, scol = (lane & 3) * 8;

#pragma unroll
    for (int i = 0; i < 2; ++i) {
        int c = wv*2 + i;
        gl_lds16(ao  + (size_t)(m0 + c*16 + srow)*DIM + scol, &a_lds[0][c*512]);
        gl_lds16(Wfh + (size_t)(n0 + c*16 + srow)*DIM + scol, &b_lds[0][c*512]);
    }
    __syncthreads();

    for (int kk = 0; kk < 16; ++kk) {
        if (kk < 15) {
            const int k1 = (kk + 1) * 32;
            const int nb = (kk + 1) & 1;
#pragma unroll
            for (int i = 0; i < 2; ++i) {
                int c = wv*2 + i;
                gl_lds16(ao  + (size_t)(m0 + c*16 + srow)*DIM + k1 + scol, &a_lds[nb][c*512]);
                gl_lds16(Wfh + (size_t)(n0 + c*16 + srow)*DIM + k1 + scol, &b_lds[nb][c*512]);
            }
        }
        const f16* al = &a_lds[kk & 1][0];
        const f16* bl = &b_lds[kk & 1][0];
        f16x8 af[4], bfr[4];
#pragma unroll
        for (int mt = 0; mt < 4; ++mt)
            af[mt]  = *(const f16x8*)&al[(wm*64 + mt*16 + mrow)*32 + qd*8];
#pragma unroll
        for (int nt = 0; nt < 4; ++nt)
            bfr[nt] = *(const f16x8*)&bl[(wn*64 + nt*16 + mrow)*32 + qd*8];
#pragma unroll
        for (int mt = 0; mt < 4; ++mt)
#pragma unroll
            for (int nt = 0; nt < 4; ++nt)
                acc[mt][nt] = __builtin_amdgcn_mfma_f32_16x16x32_f16(af[mt], bfr[nt], acc[mt][nt], 0,0,0);
        __syncthreads();
    }
#pragma unroll
    for (int mt = 0; mt < 4; ++mt)
#pragma unroll
        for (int r = 0; r < 4; ++r) {
            size_t grow = (size_t)(m0 + wm*64 + mt*16 + qd*4 + r) * DIM;
#pragma unroll
            for (int nt = 0; nt < 4; ++nt) {
                int col = n0 + wn*64 + nt*16 + mrow;
                out[grow + col] = acc[mt][nt][r] + bv[nt];
            }
        }
}

// ---------------------------------------------------------------------------
// FALLBACK projection GEMM (f32 inputs, reg-convert staging) — proven v4 path,
// used only if ws_size can't hold the f16 copies.
// ---------------------------------------------------------------------------
__global__ __launch_bounds__(256) void proj_gemm(
    const float* __restrict__ x, const float* __restrict__ y,
    const float* __restrict__ Wq, const float* __restrict__ bq,
    const float* __restrict__ Wqv, const float* __restrict__ bqv,
    const float* __restrict__ Wk, const float* __restrict__ bk,
    const float* __restrict__ Wkv, const float* __restrict__ bkv,
    f16* __restrict__ qh, f16* __restrict__ qvh,
    f16* __restrict__ kS, f16* __restrict__ vS)
{
    __shared__ __attribute__((aligned(16))) f16 a_lds[128][40];
    __shared__ __attribute__((aligned(16))) f16 b_lds[128][40];

    const int p = blockIdx.z;
    const float* A    = (p < 2) ? x : y;
    const float* W    = (p==0)?Wq:(p==1)?Wqv:(p==2)?Wk:Wkv;
    const float* bias = (p==0)?bq:(p==1)?bqv:(p==2)?bk:bkv;

    const int m0 = blockIdx.y * 128, n0 = blockIdx.x * 128;
    const int tid = threadIdx.x, lane = tid & 63, wv = tid >> 6;
    const int wm = wv >> 1, wn = wv & 1, mrow = lane & 15, qd = lane >> 4;

    f32x4 acc[4][4];
#pragma unroll
    for (int mt = 0; mt < 4; ++mt)
#pragma unroll
        for (int nt = 0; nt < 4; ++nt) acc[mt][nt] = (f32x4){0.f,0.f,0.f,0.f};

    float bv[4];
#pragma unroll
    for (int nt = 0; nt < 4; ++nt) bv[nt] = bias[n0 + wn*64 + nt*16 + mrow];

    for (int k0 = 0; k0 < DIM; k0 += 32) {
        __syncthreads();
#pragma unroll
        for (int i = 0; i < 4; ++i) {
            int c = i*256 + tid;
            int row = c >> 3, c4 = c & 7;
            float4 v = *(const float4*)(A + (size_t)(m0+row)*DIM + k0 + c4*4);
            f16x4 hh = { (f16)v.x, (f16)v.y, (f16)v.z, (f16)v.w };
            *(f16x4*)&a_lds[row][c4*4] = hh;
        }
#pragma unroll
        for (int i = 0; i < 4; ++i) {
            int c = i*256 + tid;
            int row = c >> 3, c4 = c & 7;
            float4 v = *(const float4*)(W + (size_t)(n0+row)*DIM + k0 + c4*4);
            f16x4 hh = { (f16)v.x, (f16)v.y, (f16)v.z, (f16)v.w };
            *(f16x4*)&b_lds[row][c4*4] = hh;
        }
        __syncthreads();
        f16x8 af[4], bfr[4];
#pragma unroll
        for (int mt = 0; mt < 4; ++mt) af[mt]  = *(const f16x8*)&a_lds[wm*64 + mt*16 + mrow][qd*8];
#pragma unroll
        for (int nt = 0; nt < 4; ++nt) bfr[nt] = *(const f16x8*)&b_lds[wn*64 + nt*16 + mrow][qd*8];
#pragma unroll
        for (int mt = 0; mt < 4; ++mt)
#pragma unroll
            for (int nt = 0; nt < 4; ++nt)
                acc[mt][nt] = __builtin_amdgcn_mfma_f32_16x16x32_f16(af[mt], bfr[nt], acc[mt][nt], 0,0,0);
    }

#pragma unroll
    for (int mt = 0; mt < 4; ++mt)
#pragma unroll
        for (int r = 0; r < 4; ++r) {
            int g = m0 + wm*64 + mt*16 + qd*4 + r;
#pragma unroll
            for (int nt = 0; nt < 4; ++nt) {
                int d = n0 + wn*64 + nt*16 + mrow;
                f16 val = (f16)(acc[mt][nt][r] + bv[nt]);
                if (p == 0) {
                    qh[(size_t)g*DIM + d] = val;
                } else if (p == 1) {
                    qvh[(size_t)g*DIM + d] = val;
                } else if (p == 2) {
                    int b = g >> 12, s = g & 4095;
                    int t = s >> 5, n = s & 31;
                    int chunk = d >> 8, ksl = (d >> 5) & 7, q = (d >> 3) & 3, j = d & 7;
                    size_t idx = (((size_t)((b*128 + t)*2048 + chunk*1024
                                   + n*32 + ((ksl*4 + q + n) & 31))) << 3) + j;
                    kS[idx] = val;
                } else {
                    int b = g >> 12, s = g & 4095;
                    int t = s >> 5, q = (s >> 3) & 3, j = s & 7;
                    int chunk = d >> 8, dl = d & 255;
                    size_t idx = (((size_t)((b*128 + t)*2048 + chunk*1024
                                   + dl*4 + ((q + (dl >> 1)) & 3))) << 3) + j;
                    vS[idx] = val;
                }
            }
        }
}

// ---------------------------------------------------------------------------
// Flash attention v4 (proven best, verbatim): 256 blocks (1/CU), 512 threads /
// 8 waves = 2 waves/SIMD. D-split pairs (qg, qg+4), ONE barrier per iteration,
// software-pipelined partial-S. Exchange slots double as P-transpose scratch.
// LDS: 64K kbuf + 64K vbuf + 32K xch = 163840 B (exactly 160 KiB).
// ---------------------------------------------------------------------------
__global__ __launch_bounds__(512, 2) void attn_kernel(
    const f16* __restrict__ qh, const f16* __restrict__ kS,
    const f16* __restrict__ vS, const f16* __restrict__ qvh,
    f16* __restrict__ ao)
{
    __shared__ __attribute__((aligned(16))) f16 kbuf[2][16384];   // 2 x 32KB
    __shared__ __attribute__((aligned(16))) f16 vbuf[2][16384];   // 2 x 32KB
    __shared__ __attribute__((aligned(16))) float xch[2][4][2][512]; // 32KB

    const int xcd = blockIdx.x & 7;
    const int b   = xcd >> 1;                          // batch -> XCD pair
    const int qt  = (blockIdx.x >> 3) * 2 + (xcd & 1); // 0..63
    const int tid = threadIdx.x, lane = tid & 63, w = tid >> 6;
    const int qg = w & 3, h = w >> 2;                  // Q group / d-half
    const int mrow = lane & 15, qd = lane >> 4;

    const f16* kSb = kS + ((size_t)b << 21);
    const f16* vSb = vS + ((size_t)b << 21);

    // Q fragments for this wave's 256-d half (A-layout)
    const size_t qrow = ((size_t)b*SEQ + qt*64 + qg*16 + mrow) * DIM;
    f16x8 qf[8];
#pragma unroll
    for (int i = 0; i < 8; ++i)
        qf[i] = *(const f16x8*)(qh + qrow + (h*8 + i)*32 + qd*8);

    f32x4 o[16];
#pragma unroll
    for (int nt = 0; nt < 16; ++nt) o[nt] = (f32x4){0.f,0.f,0.f,0.f};
    f32x4 o_l = (f32x4){0.f,0.f,0.f,0.f};
    float m_i[4] = {-INFINITY,-INFINITY,-INFINITY,-INFINITY};
    const f16x8 ones = {(f16)1.f,(f16)1.f,(f16)1.f,(f16)1.f,
                        (f16)1.f,(f16)1.f,(f16)1.f,(f16)1.f};

    const int n0a = mrow, n1a = 16 + mrow;
    const int cbase = h * 1024;                        // unit base of d-half chunk

    // prologue: DMA K0->kbuf0, V0->vbuf0, K1->kbuf1 (12 DMA/wave)
#pragma unroll
    for (int u = 0; u < 4; ++u) {
        const int ub = (u*8 + w) * 64;
        gl_lds16(kSb + (size_t)(ub + lane)*8,        (f16*)&kbuf[0][ub*8]);
    }
#pragma unroll
    for (int u = 0; u < 4; ++u) {
        const int ub = (u*8 + w) * 64;
        gl_lds16(vSb + (size_t)(ub + lane)*8,        (f16*)&vbuf[0][ub*8]);
    }
#pragma unroll
    for (int u = 0; u < 4; ++u) {
        const int ub = (u*8 + w) * 64;
        gl_lds16(kSb + (size_t)(2048 + ub + lane)*8, (f16*)&kbuf[1][ub*8]);
    }
    __syncthreads();

    // partial S_0 from kbuf[0]
    f32x4 s0p = (f32x4){0.f,0.f,0.f,0.f}, s1p = s0p;
    {
        const f16* kb = &kbuf[0][0];
#pragma unroll
        for (int ksl = 0; ksl < 8; ++ksl) {
            f16x8 kf0 = *(const f16x8*)&kb[(cbase + n0a*32 + ((ksl*4 + qd + n0a) & 31)) << 3];
            f16x8 kf1 = *(const f16x8*)&kb[(cbase + n1a*32 + ((ksl*4 + qd + n1a) & 31)) << 3];
            s0p = __builtin_amdgcn_mfma_f32_16x16x32_f16(qf[ksl], kf0, s0p, 0,0,0);
            s1p = __builtin_amdgcn_mfma_f32_16x16x32_f16(qf[ksl], kf1, s1p, 0,0,0);
        }
        f32x4* slot0 = (f32x4*)&xch[0][qg][h][0];
        slot0[lane]      = s0p;
        slot0[64 + lane] = s1p;
    }
    __syncthreads();

    for (int j = 0; j < 128; ++j) {
        // --- top: prefetch K(j+2) and V(j+1); drained at THIS iter's tail ---
        {
            const size_t tk = (size_t)((j + 2) & 127) * 2048;
            const size_t tv = (size_t)((j + 1) & 127) * 2048;
            f16* kd = &kbuf[j & 1][0];
            f16* vd = &vbuf[(j + 1) & 1][0];
#pragma unroll
            for (int u = 0; u < 4; ++u) {
                const int ub = (u*8 + w) * 64;
                gl_lds16(kSb + (tk + ub + lane)*8, kd + ub*8);
                gl_lds16(vSb + (tv + ub + lane)*8, vd + ub*8);
            }
        }

        // --- exchange: partner partial S_j (written iter j-1) + own regs ---
        float* slotr = &xch[j & 1][qg][h ^ 1][0];
        f32x4 s0 = ((const f32x4*)slotr)[lane];
        f32x4 s1 = ((const f32x4*)slotr)[64 + lane];
#pragma unroll
        for (int rr = 0; rr < 4; ++rr) { s0[rr] += s0p[rr]; s1[rr] += s1p[rr]; }

        // --- online softmax with defer-max (THR=8) ---
        float pm[4];
        bool need = false;
#pragma unroll
        for (int rr = 0; rr < 4; ++rr) {
            float v = fmaxf(s0[rr], s1[rr]);
            v = fmaxf(v, __shfl_xor(v, 1));
            v = fmaxf(v, __shfl_xor(v, 2));
            v = fmaxf(v, __shfl_xor(v, 4));
            v = fmaxf(v, __shfl_xor(v, 8));
            pm[rr] = v;
            if (v > m_i[rr] + 8.f) need = true;
        }
        if (__any(need)) {
#pragma unroll
            for (int rr = 0; rr < 4; ++rr) {
                float mn = fmaxf(m_i[rr], pm[rr]);
                float alpha = __expf(m_i[rr] - mn);
                m_i[rr] = mn;
#pragma unroll
                for (int nt = 0; nt < 16; ++nt) o[nt][rr] *= alpha;
                o_l[rr] *= alpha;
            }
        }
#pragma unroll
        for (int rr = 0; rr < 4; ++rr) {
            s0[rr] = __expf(s0[rr] - m_i[rr]);   // bounded by e^8
            s1[rr] = __expf(s1[rr] - m_i[rr]);
        }

        // --- P: C-layout -> A-layout via slot reuse (self-ordered in-wave) ---
        f16* pb = (f16*)slotr;                      // 16 rows x 40 f16 view
#pragma unroll
        for (int rr = 0; rr < 4; ++rr) {
            pb[(qd*4 + rr)*40 + mrow]      = (f16)s0[rr];
            pb[(qd*4 + rr)*40 + 16 + mrow] = (f16)s1[rr];
        }
        f16x8 pf = *(const f16x8*)&pb[mrow*40 + qd*8];
        o_l = __builtin_amdgcn_mfma_f32_16x16x32_f16(pf, ones, o_l, 0,0,0);

        // --- O_half += P @ V_half : 16 d-tiles ---
        {
            const f16* vb = &vbuf[j & 1][0];
#pragma unroll
            for (int nt = 0; nt < 16; ++nt) {
                int dl = nt*16 + mrow;              // d = h*256 + dl
                f16x8 vf = *(const f16x8*)&vb[(cbase + dl*4 + ((qd + (dl >> 1)) & 3)) << 3];
                o[nt] = __builtin_amdgcn_mfma_f32_16x16x32_f16(pf, vf, o[nt], 0,0,0);
            }
        }

        // --- partial S_{j+1} from kbuf[(j+1)&1] ---
        if (j < 127) {
            const f16* kb = &kbuf[(j + 1) & 1][0];
            f32x4 a0 = (f32x4){0.f,0.f,0.f,0.f}, a1 = a0;
#pragma unroll
            for (int ksl = 0; ksl < 8; ++ksl) {
                f16x8 kf0 = *(const f16x8*)&kb[(cbase + n0a*32 + ((ksl*4 + qd + n0a) & 31)) << 3];
                f16x8 kf1 = *(const f16x8*)&kb[(cbase + n1a*32 + ((ksl*4 + qd + n1a) & 31)) << 3];
                a0 = __builtin_amdgcn_mfma_f32_16x16x32_f16(qf[ksl], kf0, a0, 0,0,0);
                a1 = __builtin_amdgcn_mfma_f32_16x16x32_f16(qf[ksl], kf1, a1, 0,0,0);
            }
            s0p = a0; s1p = a1;
            f32x4* slotw = (f32x4*)&xch[(j + 1) & 1][qg][h][0];
            slotw[lane]      = s0p;
            slotw[64 + lane] = s1p;
        }

        __syncthreads();   // sole barrier: xch visible + DMA drained (full cover)
    }

    // epilogue: each wave owns rows [qg*16,+16) x cols [h*256,+256) fully
#pragma unroll
    for (int rr = 0; rr < 4; ++rr) {
        float inv_l = 1.f / o_l[rr];
        size_t grow = ((size_t)b*SEQ + qt*64 + qg*16 + qd*4 + rr) * DIM + h*256;
#pragma unroll
        for (int nt = 0; nt < 16; ++nt) {
            int col = nt*16 + mrow;
            float val = o[nt][rr] * inv_l + (float)qvh[grow + col];
            ao[grow + col] = (f16)val;
        }
    }
}

// ---------------------------------------------------------------------------
// FALLBACK final linear (f32 W): out = sum_k ao[m,k]*Wf[n,k] + bf[n]
// ---------------------------------------------------------------------------
__global__ __launch_bounds__(256) void final_gemm(
    const f16* __restrict__ ao, const float* __restrict__ Wf,
    const float* __restrict__ bf, float* __restrict__ out)
{
    __shared__ __attribute__((aligned(16))) f16 a_lds[128][40];
    __shared__ __attribute__((aligned(16))) f16 b_lds[128][40];

    const int m0 = blockIdx.y * 128, n0 = blockIdx.x * 128;
    const int tid = threadIdx.x, lane = tid & 63, wv = tid >> 6;
    const int wm = wv >> 1, wn = wv & 1, mrow = lane & 15, qd = lane >> 4;

    f32x4 acc[4][4];
#pragma unroll
    for (int mt = 0; mt < 4; ++mt)
#pragma unroll
        for (int nt = 0; nt < 4; ++nt) acc[mt][nt] = (f32x4){0.f,0.f,0.f,0.f};

    float bv[4];
#pragma unroll
    for (int nt = 0; nt < 4; ++nt) bv[nt] = bf[n0 + wn*64 + nt*16 + mrow];

    for (int k0 = 0; k0 < DIM; k0 += 32) {
        __syncthreads();
#pragma unroll
        for (int i = 0; i < 2; ++i) {
            int c = i*256 + tid;
            int row = c >> 2, c8 = c & 3;
            *(f16x8*)&a_lds[row][c8*8] =
                *(const f16x8*)(ao + (size_t)(m0+row)*DIM + k0 + c8*8);
        }
#pragma unroll
        for (int i = 0; i < 4; ++i) {
            int c = i*256 + tid;
            int row = c >> 3, c4 = c & 7;
            float4 v = *(const float4*)(Wf + (size_t)(n0+row)*DIM + k0 + c4*4);
            f16x4 hh = { (f16)v.x, (f16)v.y, (f16)v.z, (f16)v.w };
            *(f16x4*)&b_lds[row][c4*4] = hh;
        }
        __syncthreads();
        f16x8 af[4], bfr[4];
#pragma unroll
        for (int mt = 0; mt < 4; ++mt) af[mt]  = *(const f16x8*)&a_lds[wm*64 + mt*16 + mrow][qd*8];
#pragma unroll
        for (int nt = 0; nt < 4; ++nt) bfr[nt] = *(const f16x8*)&b_lds[wn*64 + nt*16 + mrow][qd*8];
#pragma unroll
        for (int mt = 0; mt < 4; ++mt)
#pragma unroll
            for (int nt = 0; nt < 4; ++nt)
                acc[mt][nt] = __builtin_amdgcn_mfma_f32_16x16x32_f16(af[mt], bfr[nt], acc[mt][nt], 0,0,0);
    }
#pragma unroll
    for (int mt = 0; mt < 4; ++mt)
#pragma unroll
        for (int r = 0; r < 4; ++r) {
            size_t grow = (size_t)(m0 + wm*64 + mt*16 + qd*4 + r) * DIM;
#pragma unroll
            for (int nt = 0; nt < 4; ++nt) {
                int col = n0 + wn*64 + nt*16 + mrow;
                out[grow + col] = acc[mt][nt][r] + bv[nt];
            }
        }
}

// ---------------------------------------------------------------------------
extern "C" void kernel_launch(void* const* d_in, const int* in_sizes, int n_in,
                              void* d_out, int out_size, void* d_ws, size_t ws_size,
                              hipStream_t stream)
{
    const float* x   = (const float*)d_in[0];
    const float* y   = (const float*)d_in[1];
    const float* Wq  = (const float*)d_in[2];
    const float* bq  = (const float*)d_in[3];
    const float* Wqv = (const float*)d_in[4];
    const float* bqv = (const float*)d_in[5];
    const float* Wk  = (const float*)d_in[6];
    const float* bk  = (const float*)d_in[7];
    const float* Wkv = (const float*)d_in[8];
    const float* bkv = (const float*)d_in[9];
    const float* Wf  = (const float*)d_in[10];
    const float* bf  = (const float*)d_in[11];
    float* out = (float*)d_out;

    f16* qh  = (f16*)d_ws;       // base: 5 x NEL f16 = 84 MB (proven layout)
    f16* qvh = qh  + NEL;
    f16* kS  = qvh + NEL;
    f16* vS  = kS  + NEL;
    f16* aob = vS  + NEL;
    // fast-path extras:
    f16* xh  = aob + NEL;
    f16* yh  = xh  + NEL;
    f16* Wh  = yh  + NEL;        // [5][512*512]

    const size_t need_fast = (7*NEL + 5*WELEM) * sizeof(f16);
    const bool fast = (ws_size >= need_fast);

    if (fast) {
        convert_kernel<<<2048, 256, 0, stream>>>(x, y, Wq, Wqv, Wk, Wkv, Wf, xh, yh, Wh);
        proj_gemm16<<<dim3(4, 128, 4), 256, 0, stream>>>(
            xh, yh, Wh, bq, bqv, bk, bkv, qh, qvh, kS, vS);
    } else {
        proj_gemm<<<dim3(4, 128, 4), 256, 0, stream>>>(
            x, y, Wq, bq, Wqv, bqv, Wk, bk, Wkv, bkv, qh, qvh, kS, vS);
    }

    attn_kernel<<<dim3(256), 512, 0, stream>>>(qh, kS, vS, qvh, aob);

    if (fast) {
        final_gemm16<<<dim3(4, 128), 256, 0, stream>>>(aob, Wh + 4*WELEM, bf, out);
    } else {
        final_gemm<<<dim3(4, 128), 256, 0, stream>>>(aob, Wf, bf, out);
    }
}